// Round 19
// baseline (714.750 us; speedup 1.0000x reference)
//
#include <hip/hip_runtime.h>

typedef unsigned short u16;
typedef __attribute__((ext_vector_type(8))) short s16x8;
typedef __attribute__((ext_vector_type(4))) short s16x4;
typedef __attribute__((ext_vector_type(4))) float f32x4;

#define DEVI static __device__ __forceinline__

constexpr int BATCH = 2;
constexpr int SEQ   = 2048;
constexpr int EMB   = 4096;
constexpr int NQ    = 32;
constexpr int NKV   = 8;
constexpr int HD    = 128;
constexpr int KVD   = 1024;
constexpr int MR    = BATCH * SEQ;   // 4096 rows for all projections

// softmax scale * log2(e), pre-folded into Wq/bq at weight-transpose time
constexpr float SCL = 0.08838834764831845f * 1.4426950408889634f;

// ---------- helpers ----------

DEVI u16 f2bf(float f) {             // RNE float -> bf16 (finite inputs)
  union { float f; unsigned u; } x; x.f = f;
  unsigned r = x.u + 0x7FFFu + ((x.u >> 16) & 1u);
  return (u16)(r >> 16);
}

DEVI void mfma_acc(f32x4& c, s16x8 a, s16x8 b) {
  asm volatile("v_mfma_f32_16x16x32_bf16 %0, %1, %2, %0" : "+v"(c) : "v"(a), "v"(b));
}

DEVI void gload16(const void* g, void* l) {
  __builtin_amdgcn_global_load_lds(
      (const __attribute__((address_space(1))) void*)g,
      (__attribute__((address_space(3))) void*)l, 16, 0, 0);
}

DEVI float fexp2(float x) {
#if __has_builtin(__builtin_amdgcn_exp2f)
  return __builtin_amdgcn_exp2f(x);
#else
  return exp2f(x);
#endif
}

DEVI void store_out(u16* C, size_t idx, float v)   { C[idx] = f2bf(v); }
DEVI void store_out(float* C, size_t idx, float v) { C[idx] = v; }

// ---------- fused prep: 3x f32->bf16 cvt + 4x weight transpose, ONE launch ----------
// (R15-validated.)

__global__ __launch_bounds__(256) void prep(
    const float* __restrict__ q_in, const float* __restrict__ k_in,
    const float* __restrict__ v_in,
    u16* __restrict__ qb, u16* __restrict__ kb, u16* __restrict__ vb,
    const float* __restrict__ Wq, const float* __restrict__ Wo,
    const float* __restrict__ Wk, const float* __restrict__ Wv,
    u16* __restrict__ Tq, u16* __restrict__ To,
    u16* __restrict__ Tk, u16* __restrict__ Tv) {
  __shared__ u16 tile[32][33];
  const int tid = threadIdx.x;
  int id = blockIdx.x;

  if (id < 24576) {                       // ---- cvt role ----
    const int tn = id >> 13;              // id / 8192
    const float* in = (tn == 0) ? q_in : (tn == 1) ? k_in : v_in;
    u16* out = (tn == 0) ? qb : (tn == 1) ? kb : vb;
    const size_t i = (size_t)(id & 8191) * 256 + tid;
    const float4* p4 = (const float4*)in;
    float4 x = p4[2 * i], y = p4[2 * i + 1];
    u16 t[8];
    t[0] = f2bf(x.x); t[1] = f2bf(x.y); t[2] = f2bf(x.z); t[3] = f2bf(x.w);
    t[4] = f2bf(y.x); t[5] = f2bf(y.y); t[6] = f2bf(y.z); t[7] = f2bf(y.w);
    *(s16x8*)(out + 8 * i) = *(const s16x8*)t;
    return;
  }

  // ---- transpose role ----
  id -= 24576;
  int z, rem;
  if (id < 16384)      { z = 0; rem = id; }
  else if (id < 32768) { z = 1; rem = id - 16384; }
  else if (id < 36864) { z = 2; rem = id - 32768; }
  else                 { z = 3; rem = id - 36864; }
  const int nt = (z < 2) ? 128 : 32;      // x-tiles = Nd/32
  const int Nd = (z < 2) ? EMB : KVD;
  const int bx = rem % nt, by = rem / nt;
  const float* W = (z == 0) ? Wq : (z == 1) ? Wo : (z == 2) ? Wk : Wv;
  u16* Wt = (z == 0) ? Tq : (z == 1) ? To : (z == 2) ? Tk : Tv;
  const float s = (z == 0) ? SCL : 1.0f;
  const int tx = tid & 31, ty = tid >> 5;
  const int n0 = bx * 32, k0 = by * 32;
#pragma unroll
  for (int j = 0; j < 4; ++j)
    tile[ty + 8 * j][tx] = f2bf(W[(size_t)(k0 + ty + 8 * j) * Nd + n0 + tx] * s);
  __syncthreads();
#pragma unroll
  for (int j = 0; j < 4; ++j)
    Wt[(size_t)(n0 + ty + 8 * j) * EMB + k0 + tx] = tile[tx][ty + 8 * j];
}

// ---------- GEMM body: BK=64 formulas (R11-R13, 0 bank conflicts, half the
// barriers) x counted-vmcnt double-buffer skeleton (R18, correctness-validated).
// Per K-step: issue next slab's 8 gloads -> s_waitcnt vmcnt(8) (oldest 8 = cur
// slab landed; 16 outstanding cap) -> raw s_barrier -> 16 ds_read_b128 + 32
// MFMA -> raw s_barrier. No vmcnt(0) drain in the loop. LDS 2x32 KiB.
// MODE 0: normal store. MODE 1: V-proj direct-transposed store (R13-validated).

template <typename OT, int MODE>
DEVI void gemm_body(const u16* __restrict__ A, const u16* __restrict__ Bt,
                    const float* __restrict__ bias, float bscl, OT* __restrict__ C,
                    int M, int N, int K, int m0, int n0,
                    u16* As, u16* Bs) {
  const int tid = threadIdx.x;
  const int lane = tid & 63, w = tid >> 6;
  const int wr = w >> 1, wc = w & 1;
  const int l15 = lane & 15, g = lane >> 4;
  const int srow = lane >> 3;          // 0..7 within a wave's 8-row group
  const int schunk = lane & 7;         // 8 chunks of 16B per 128B row

  f32x4 acc[4][4] = {};

  const u16* Ag = A  + (size_t)(m0 + w * 8 + srow) * K + ((schunk ^ srow) << 3);
  const u16* Bg = Bt + (size_t)(n0 + w * 8 + srow) * K + ((schunk ^ srow) << 3);

  auto stage = [&](int buf, int k0) {
    u16* Al = As + buf * 8192 + w * 512;
    u16* Bl = Bs + buf * 8192 + w * 512;
#pragma unroll
    for (int p = 0; p < 4; ++p) {
      gload16(Ag + (size_t)(p * 32) * K + k0, Al + p * 2048);
      gload16(Bg + (size_t)(p * 32) * K + k0, Bl + p * 2048);
    }
  };

  stage(0, 0);
  const int ns = K >> 6;
  for (int s = 0; s < ns; ++s) {
    const int cur = s & 1;
    if (s + 1 < ns) {
      stage(cur ^ 1, (s + 1) << 6);                       // next slab flies
      asm volatile("s_waitcnt vmcnt(8)" ::: "memory");    // cur slab landed
    } else {
      asm volatile("s_waitcnt vmcnt(0)" ::: "memory");    // final slab landed
    }
    __builtin_amdgcn_sched_barrier(0);
    __builtin_amdgcn_s_barrier();                         // all waves: cur resident
    __builtin_amdgcn_sched_barrier(0);

    const u16* Ab = As + cur * 8192;
    const u16* Bb = Bs + cur * 8192;
#pragma unroll
    for (int ks = 0; ks < 2; ++ks) {
      s16x8 af[4], bfr[4];
#pragma unroll
      for (int rt = 0; rt < 4; ++rt) {
        const int blk = ((ks << 2) | g) ^ (l15 & 7);
        af[rt] = *(const s16x8*)(Ab + (wr * 64 + rt * 16 + l15) * 64 + (blk << 3));
      }
#pragma unroll
      for (int ct = 0; ct < 4; ++ct) {
        const int blk = ((ks << 2) | g) ^ (l15 & 7);
        bfr[ct] = *(const s16x8*)(Bb + (wc * 64 + ct * 16 + l15) * 64 + (blk << 3));
      }
#pragma unroll
      for (int rt = 0; rt < 4; ++rt)
#pragma unroll
        for (int ct = 0; ct < 4; ++ct)
          mfma_acc(acc[rt][ct], af[rt], bfr[ct]);
    }

    __builtin_amdgcn_sched_barrier(0);
    __builtin_amdgcn_s_barrier();                         // all reads of cur done
    __builtin_amdgcn_sched_barrier(0);
  }

#pragma unroll
  for (int ct = 0; ct < 4; ++ct) {
    const int col = n0 + wc * 64 + ct * 16 + l15;
    const float bv = bias[col] * bscl;
#pragma unroll
    for (int rt = 0; rt < 4; ++rt) {
      const int row0 = m0 + wr * 64 + rt * 16 + g * 4;
      if constexpr (MODE == 0) {
#pragma unroll
        for (int i = 0; i < 4; ++i)
          store_out(C, (size_t)(row0 + i) * N + col, acc[rt][ct][i] + bv);
      } else {
        const int b = row0 >> 11, s0 = row0 & 2047;
        const int h = col >> 7, d = col & 127;
        u16 t4[4];
#pragma unroll
        for (int i = 0; i < 4; ++i) t4[i] = f2bf(acc[rt][ct][i] + bv);
        *(s16x4*)((u16*)C + ((size_t)(b * NKV + h) * HD + d) * SEQ + s0) =
            *(const s16x4*)t4;
      }
    }
  }
}

// O-proj with XCD-aware bijective remap (R10-R17-validated).
__global__ __launch_bounds__(256) void gemm_o(const u16* __restrict__ A,
                                              const u16* __restrict__ Bt,
                                              const float* __restrict__ bias,
                                              float* __restrict__ C) {
  __shared__ __align__(16) u16 As[2 * 128 * 64];
  __shared__ __align__(16) u16 Bs[2 * 128 * 64];
  const int d = blockIdx.x + blockIdx.y * 32;
  const int t = (d & 7) * 128 + (d >> 3);
  const int x = t >> 5, y = t & 31;
  gemm_body<float, 0>(A, Bt, bias, 1.0f, C, MR, EMB, EMB, y * 128, x * 128, As, Bs);
}

// Merged QKV projection with XCD remap (R9-R17-validated pointer selection).
__global__ __launch_bounds__(256) void gemm_proj(
    const u16* __restrict__ qb, const u16* __restrict__ kb, const u16* __restrict__ vb,
    const u16* __restrict__ Wqt, const u16* __restrict__ Wkt, const u16* __restrict__ Wvt,
    const float* __restrict__ bq, const float* __restrict__ bk, const float* __restrict__ bv,
    u16* __restrict__ Qp, u16* __restrict__ Kpp, u16* __restrict__ Vtt) {
  __shared__ __align__(16) u16 As[2 * 128 * 64];
  __shared__ __align__(16) u16 Bs[2 * 128 * 64];
  const int d = blockIdx.x + blockIdx.y * 48;
  const int t = (d & 7) * 192 + (d >> 3);
  const int x = t >> 5, y = t & 31;
  if (x < 32)
    gemm_body<u16, 0>(qb, Wqt, bq, SCL, Qp, MR, EMB, EMB, y * 128, x * 128, As, Bs);
  else if (x < 40)
    gemm_body<u16, 0>(kb, Wkt, bk, 1.0f, Kpp, MR, KVD, EMB, y * 128, (x - 32) * 128, As, Bs);
  else
    gemm_body<u16, 1>(vb, Wvt, bv, 1.0f, Vtt, MR, KVD, EMB, y * 128, (x - 40) * 128, As, Bs);
}

// ---------- flash attention (GQA), swapped-operand structure ----------
// R17-VERBATIM (passing): R15 body + XCD-aware flat block-id decode.

__global__ __launch_bounds__(256, 2) void attn(const u16* __restrict__ Q,
                                               const u16* __restrict__ Kp,
                                               const u16* __restrict__ Vt,
                                               u16* __restrict__ Y) {
  __shared__ __align__(16) u16 Kb[2][64 * 128];   // [buf][kv][d]  (swizzled f=r&7)
  __shared__ __align__(16) u16 Vb[2][128 * 64];   // [buf][d][kv]  (swizzled f=r&7)

  const int tid = threadIdx.x, lane = tid & 63, w = tid >> 6;
  const int l15 = lane & 15, g = lane >> 4;
  const int d_ = blockIdx.x;
  const int t_ = (d_ & 7) * 128 + (d_ >> 3);      // XCD-aware bijective remap
  const int bz = t_ >> 4, b = bz >> 5, qh = bz & 31, h = qh >> 2;
  const int q0 = (t_ & 15) * 128;

  // Q fragments (B-operand layout: lane holds Q[q=l15][k=g*8..g*8+7])
  s16x8 qf[2][4];
  const u16* qptr = Q + (size_t)(b * SEQ + q0 + w * 32) * EMB + qh * HD;
#pragma unroll
  for (int rt = 0; rt < 2; ++rt)
#pragma unroll
    for (int ks = 0; ks < 4; ++ks)
      qf[rt][ks] = *(const s16x8*)(qptr + (size_t)(rt * 16 + l15) * EMB + ks * 32 + g * 8);

  const u16* kbase = Kp + (size_t)b * SEQ * KVD + h * HD;
  const u16* vbase = Vt + (size_t)(b * NKV + h) * HD * SEQ;

  // Stage one KV chunk into buf via global_load_lds (R2 verbatim).
  auto stage = [&](int buf, int kv0) {
#pragma unroll
    for (int p = 0; p < 4; ++p) {               // K: 64 rows x 128 u16
      int r = p * 16 + w * 4 + (lane >> 4);
      const u16* src = kbase + (size_t)(kv0 + r) * KVD + (((lane & 15) ^ (r & 7)) << 3);
      gload16(src, &Kb[buf][p * 2048 + w * 512]);
    }
#pragma unroll
    for (int p = 0; p < 4; ++p) {               // V^T: 128 rows x 64 u16
      int r = p * 32 + w * 8 + (lane >> 3);
      const u16* src = vbase + (size_t)r * SEQ + kv0 + (((lane & 7) ^ (r & 7)) << 3);
      gload16(src, &Vb[buf][p * 2048 + w * 512]);
    }
  };

  f32x4 o[2][8] = {};
  float m_[2] = {-1e30f, -1e30f}, l_[2] = {0.f, 0.f};

  stage(0, 0);
  __syncthreads();

  for (int t = 0; t < SEQ / 64; ++t) {
    const int cur = t & 1;
    if (t < SEQ / 64 - 1) stage(cur ^ 1, (t + 1) * 64);  // prefetch next chunk

    // ---- S^T = K Q^T  (4 kv col-tiles x 2 q row-tiles) ----
    f32x4 sacc[2][4] = {};
    __builtin_amdgcn_s_setprio(1);
#pragma unroll
    for (int ks = 0; ks < 4; ++ks) {
      s16x8 kf[4];
#pragma unroll
      for (int ct = 0; ct < 4; ++ct) {
        const int blk = ((ks << 2) | g) ^ (l15 & 7);
        kf[ct] = *(const s16x8*)&Kb[cur][(ct * 16 + l15) * 128 + (blk << 3)];
      }
#pragma unroll
      for (int rt = 0; rt < 2; ++rt)
#pragma unroll
        for (int ct = 0; ct < 4; ++ct)
          mfma_acc(sacc[rt][ct], kf[ct], qf[rt][ks]);
    }
    __builtin_amdgcn_s_setprio(0);

    // ---- online softmax (scores already in log2 domain): defer-max, per-lane l ----
    s16x8 pvf[2][2];
#pragma unroll
    for (int rt = 0; rt < 2; ++rt) {
      float t0 = fmaxf(fmaxf(sacc[rt][0][0], sacc[rt][0][1]),
                       fmaxf(sacc[rt][0][2], sacc[rt][0][3]));
      float t1 = fmaxf(fmaxf(sacc[rt][1][0], sacc[rt][1][1]),
                       fmaxf(sacc[rt][1][2], sacc[rt][1][3]));
      float t2 = fmaxf(fmaxf(sacc[rt][2][0], sacc[rt][2][1]),
                       fmaxf(sacc[rt][2][2], sacc[rt][2][3]));
      float t3 = fmaxf(fmaxf(sacc[rt][3][0], sacc[rt][3][1]),
                       fmaxf(sacc[rt][3][2], sacc[rt][3][3]));
      const float pm = fmaxf(fmaxf(t0, t1), fmaxf(t2, t3));

      if (!__all(pm - m_[rt] <= 8.f)) {        // rare: genuine max growth
        float mr = pm;
        mr = fmaxf(mr, __shfl_xor(mr, 16));
        mr = fmaxf(mr, __shfl_xor(mr, 32));
        const float mn = fmaxf(m_[rt], mr);
        const float al = fexp2(m_[rt] - mn);
        m_[rt] = mn;
        l_[rt] *= al;
#pragma unroll
        for (int dt = 0; dt < 8; ++dt) {
          o[rt][dt][0] *= al; o[rt][dt][1] *= al;
          o[rt][dt][2] *= al; o[rt][dt][3] *= al;
        }
      }
      const float mcur = m_[rt];

      float rs = 0.f;
      int wd[4][2];
#pragma unroll
      for (int ct = 0; ct < 4; ++ct) {
        float p0 = fexp2(sacc[rt][ct][0] - mcur);
        float p1 = fexp2(sacc[rt][ct][1] - mcur);
        float p2 = fexp2(sacc[rt][ct][2] - mcur);
        float p3 = fexp2(sacc[rt][ct][3] - mcur);
        rs += (p0 + p1) + (p2 + p3);
        asm("v_cvt_pk_bf16_f32 %0, %1, %2" : "=v"(wd[ct][0]) : "v"(p0), "v"(p1));
        asm("v_cvt_pk_bf16_f32 %0, %1, %2" : "=v"(wd[ct][1]) : "v"(p2), "v"(p3));
      }
      l_[rt] += rs;                            // per-lane partial; reduced in epilogue

      // route P^T into PV B-fragments: target lane [g1,g0] word (u,s) <- reg
      // (g1,s) lane [g0,u]; swap32 then swap16 realizes the quarter permutation.
#pragma unroll
      for (int ks2 = 0; ks2 < 2; ++ks2) {
        union { int w4[4]; s16x8 v; } u;
#pragma unroll
        for (int s = 0; s < 2; ++s) {
          int x = wd[2 * ks2][s], y = wd[2 * ks2 + 1][s];
          asm volatile("v_permlane32_swap_b32 %0, %1" : "+v"(x), "+v"(y));
          asm volatile("v_permlane16_swap_b32 %0, %1" : "+v"(x), "+v"(y));
          u.w4[s] = x; u.w4[2 + s] = y;
        }
        pvf[rt][ks2] = u.v;
      }
    }

    // ---- O^T += V^T P^T ----
    __builtin_amdgcn_s_setprio(1);
#pragma unroll
    for (int ks2 = 0; ks2 < 2; ++ks2)
#pragma unroll
      for (int dt = 0; dt < 8; ++dt) {
        const int blk = ((ks2 << 2) | g) ^ (l15 & 7);
        const s16x8 vf = *(const s16x8*)&Vb[cur][(dt * 16 + l15) * 64 + (blk << 3)];
        mfma_acc(o[0][dt], vf, pvf[0][ks2]);
        mfma_acc(o[1][dt], vf, pvf[1][ks2]);
      }
    __builtin_amdgcn_s_setprio(0);

    __syncthreads();   // staged chunk t+1 visible; all reads of buf done
  }

  // ---- epilogue: reduce l across g-lanes once, then 8B vector stores ----
  u16* ybase = Y + (size_t)(b * SEQ + q0 + w * 32) * EMB + qh * HD;
#pragma unroll
  for (int rt = 0; rt < 2; ++rt) {
    float lt = l_[rt];
    lt += __shfl_xor(lt, 16);
    lt += __shfl_xor(lt, 32);
    const float inv = 1.f / lt;
    u16* yr = ybase + (size_t)(rt * 16 + l15) * EMB + g * 4;
#pragma unroll
    for (int dt = 0; dt < 8; ++dt) {
      u16 t4[4];
#pragma unroll
      for (int i = 0; i < 4; ++i) t4[i] = f2bf(o[rt][dt][i] * inv);
      *(s16x4*)(yr + dt * 16) = *(const s16x4*)t4;
    }
  }
}

// ---------- launch ----------

extern "C" void kernel_launch(void* const* d_in, const int* in_sizes, int n_in,
                              void* d_out, int out_size, void* d_ws, size_t ws_size,
                              hipStream_t stream) {
  (void)in_sizes; (void)n_in; (void)out_size;
  const float* q_in = (const float*)d_in[0];
  const float* k_in = (const float*)d_in[1];
  const float* v_in = (const float*)d_in[2];
  const float* Wq = (const float*)d_in[3];
  const float* bq = (const float*)d_in[4];
  const float* Wk = (const float*)d_in[5];
  const float* bk = (const float*)d_in[6];
  const float* Wv = (const float*)d_in[7];
  const float* bv = (const float*)d_in[8];
  const float* Wo = (const float*)d_in[9];
  const float* bo = (const float*)d_in[10];
  float* out = (float*)d_out;

  char* base = (char*)d_ws;
  size_t off = 0;
  auto alloc = [&](size_t bytes) -> void* {
    void* r = base + off;
    off += (bytes + 255) & ~(size_t)255;
    return r;
  };
  u16* qb  = (u16*)alloc((size_t)MR * EMB * 2);
  u16* kb  = (u16*)alloc((size_t)MR * EMB * 2);
  u16* vb  = (u16*)alloc((size_t)MR * EMB * 2);
  u16* Wqt = (u16*)alloc((size_t)EMB * EMB * 2);
  u16* Wkt = (u16*)alloc((size_t)KVD * EMB * 2);
  u16* Wvt = (u16*)alloc((size_t)KVD * EMB * 2);
  u16* Wot = (u16*)alloc((size_t)EMB * EMB * 2);
  u16* Qp  = (u16*)alloc((size_t)MR * EMB * 2);
  u16* Kpp = (u16*)alloc((size_t)MR * KVD * 2);
  u16* Vtt = (u16*)alloc((size_t)MR * KVD * 2);
  u16* Y   = qb;  // qb dead after Q projection
  if (off > ws_size) return;  // loud failure instead of OOB corruption

  prep<<<65536, 256, 0, stream>>>(q_in, k_in, v_in, qb, kb, vb,
                                  Wq, Wo, Wk, Wv, Wqt, Wot, Wkt, Wvt);

  gemm_proj<<<dim3(48, 32), 256, 0, stream>>>(qb, kb, vb, Wqt, Wkt, Wvt,
                                              bq, bk, bv, Qp, Kpp, Vtt);
  attn<<<1024, 256, 0, stream>>>(Qp, Kpp, Vtt, Y);
  gemm_o<<<dim3(32, 32), 256, 0, stream>>>(Y, Wot, bo, out);
}

// Round 20
// 633.395 us; speedup vs baseline: 1.1284x; 1.1284x over previous
//
#include <hip/hip_runtime.h>

typedef unsigned short u16;
typedef __attribute__((ext_vector_type(8))) short s16x8;
typedef __attribute__((ext_vector_type(4))) short s16x4;
typedef __attribute__((ext_vector_type(4))) float f32x4;

#define DEVI static __device__ __forceinline__

constexpr int BATCH = 2;
constexpr int SEQ   = 2048;
constexpr int EMB   = 4096;
constexpr int NQ    = 32;
constexpr int NKV   = 8;
constexpr int HD    = 128;
constexpr int KVD   = 1024;
constexpr int MR    = BATCH * SEQ;   // 4096 rows for all projections

// softmax scale * log2(e), pre-folded into Wq/bq at weight-transpose time
constexpr float SCL = 0.08838834764831845f * 1.4426950408889634f;

// ---------- helpers ----------

DEVI u16 f2bf(float f) {             // RNE float -> bf16 (finite inputs)
  union { float f; unsigned u; } x; x.f = f;
  unsigned r = x.u + 0x7FFFu + ((x.u >> 16) & 1u);
  return (u16)(r >> 16);
}

DEVI void mfma_acc(f32x4& c, s16x8 a, s16x8 b) {
  asm volatile("v_mfma_f32_16x16x32_bf16 %0, %1, %2, %0" : "+v"(c) : "v"(a), "v"(b));
}

DEVI void gload16(const void* g, void* l) {
  __builtin_amdgcn_global_load_lds(
      (const __attribute__((address_space(1))) void*)g,
      (__attribute__((address_space(3))) void*)l, 16, 0, 0);
}

DEVI float fexp2(float x) {
#if __has_builtin(__builtin_amdgcn_exp2f)
  return __builtin_amdgcn_exp2f(x);
#else
  return exp2f(x);
#endif
}

DEVI void store_out(u16* C, size_t idx, float v)   { C[idx] = f2bf(v); }
DEVI void store_out(float* C, size_t idx, float v) { C[idx] = v; }

// ---------- fused prep: 3x f32->bf16 cvt + 4x weight transpose, ONE launch ----------
// (R15-validated; at the HBM roofline ~70us.)

__global__ __launch_bounds__(256) void prep(
    const float* __restrict__ q_in, const float* __restrict__ k_in,
    const float* __restrict__ v_in,
    u16* __restrict__ qb, u16* __restrict__ kb, u16* __restrict__ vb,
    const float* __restrict__ Wq, const float* __restrict__ Wo,
    const float* __restrict__ Wk, const float* __restrict__ Wv,
    u16* __restrict__ Tq, u16* __restrict__ To,
    u16* __restrict__ Tk, u16* __restrict__ Tv) {
  __shared__ u16 tile[32][33];
  const int tid = threadIdx.x;
  int id = blockIdx.x;

  if (id < 24576) {                       // ---- cvt role ----
    const int tn = id >> 13;              // id / 8192
    const float* in = (tn == 0) ? q_in : (tn == 1) ? k_in : v_in;
    u16* out = (tn == 0) ? qb : (tn == 1) ? kb : vb;
    const size_t i = (size_t)(id & 8191) * 256 + tid;
    const float4* p4 = (const float4*)in;
    float4 x = p4[2 * i], y = p4[2 * i + 1];
    u16 t[8];
    t[0] = f2bf(x.x); t[1] = f2bf(x.y); t[2] = f2bf(x.z); t[3] = f2bf(x.w);
    t[4] = f2bf(y.x); t[5] = f2bf(y.y); t[6] = f2bf(y.z); t[7] = f2bf(y.w);
    *(s16x8*)(out + 8 * i) = *(const s16x8*)t;
    return;
  }

  // ---- transpose role ----
  id -= 24576;
  int z, rem;
  if (id < 16384)      { z = 0; rem = id; }
  else if (id < 32768) { z = 1; rem = id - 16384; }
  else if (id < 36864) { z = 2; rem = id - 32768; }
  else                 { z = 3; rem = id - 36864; }
  const int nt = (z < 2) ? 128 : 32;      // x-tiles = Nd/32
  const int Nd = (z < 2) ? EMB : KVD;
  const int bx = rem % nt, by = rem / nt;
  const float* W = (z == 0) ? Wq : (z == 1) ? Wo : (z == 2) ? Wk : Wv;
  u16* Wt = (z == 0) ? Tq : (z == 1) ? To : (z == 2) ? Tk : Tv;
  const float s = (z == 0) ? SCL : 1.0f;
  const int tx = tid & 31, ty = tid >> 5;
  const int n0 = bx * 32, k0 = by * 32;
#pragma unroll
  for (int j = 0; j < 4; ++j)
    tile[ty + 8 * j][tx] = f2bf(W[(size_t)(k0 + ty + 8 * j) * Nd + n0 + tx] * s);
  __syncthreads();
#pragma unroll
  for (int j = 0; j < 4; ++j)
    Wt[(size_t)(n0 + ty + 8 * j) * EMB + k0 + tx] = tile[tx][ty + 8 * j];
}

// ---------- GEMM body, BK=64, single-buffer: the MEASURED FAMILY OPTIMUM ----------
// (R13/R15-validated, 221us/934TF on gemm_proj.) Full {BK, buffering} matrix
// measured R11-R19: BK32/single 280, BK64/single 221, BK32/dbuf 299,
// BK64/dbuf-drain 288, BK64/dbuf-counted 291. At 128^2/4-wave, inter-block TLP
// (5 blocks/CU @ 32 KiB LDS) dominates any pipelining that halves residency.
// MODE 0: normal store. MODE 1: V-proj direct-transposed store into
// Vt[B*NKV][HD][SEQ] (R13-validated).

template <typename OT, int MODE>
DEVI void gemm_body(const u16* __restrict__ A, const u16* __restrict__ Bt,
                    const float* __restrict__ bias, float bscl, OT* __restrict__ C,
                    int M, int N, int K, int m0, int n0,
                    u16* As, u16* Bs) {
  const int tid = threadIdx.x;
  const int lane = tid & 63, w = tid >> 6;
  const int wr = w >> 1, wc = w & 1;
  const int l15 = lane & 15, g = lane >> 4;
  const int srow = lane >> 3;          // 0..7 within a wave's 8-row group
  const int schunk = lane & 7;         // 8 chunks of 16B per 128B row

  f32x4 acc[4][4] = {};

  const u16* Ag = A  + (size_t)(m0 + w * 8 + srow) * K + ((schunk ^ srow) << 3);
  const u16* Bg = Bt + (size_t)(n0 + w * 8 + srow) * K + ((schunk ^ srow) << 3);
  u16* Al = As + w * 512;
  u16* Bl = Bs + w * 512;

  for (int k0 = 0; k0 < K; k0 += 64) {
    __syncthreads();
#pragma unroll
    for (int p = 0; p < 4; ++p) {
      gload16(Ag + (size_t)(p * 32) * K + k0, Al + p * 2048);
      gload16(Bg + (size_t)(p * 32) * K + k0, Bl + p * 2048);
    }
    __syncthreads();

#pragma unroll
    for (int ks = 0; ks < 2; ++ks) {
      s16x8 af[4], bfr[4];
#pragma unroll
      for (int rt = 0; rt < 4; ++rt) {
        const int blk = ((ks << 2) | g) ^ (l15 & 7);
        af[rt] = *(const s16x8*)(As + (wr * 64 + rt * 16 + l15) * 64 + (blk << 3));
      }
#pragma unroll
      for (int ct = 0; ct < 4; ++ct) {
        const int blk = ((ks << 2) | g) ^ (l15 & 7);
        bfr[ct] = *(const s16x8*)(Bs + (wc * 64 + ct * 16 + l15) * 64 + (blk << 3));
      }
#pragma unroll
      for (int rt = 0; rt < 4; ++rt)
#pragma unroll
        for (int ct = 0; ct < 4; ++ct)
          mfma_acc(acc[rt][ct], af[rt], bfr[ct]);
    }
  }

#pragma unroll
  for (int ct = 0; ct < 4; ++ct) {
    const int col = n0 + wc * 64 + ct * 16 + l15;
    const float bv = bias[col] * bscl;
#pragma unroll
    for (int rt = 0; rt < 4; ++rt) {
      const int row0 = m0 + wr * 64 + rt * 16 + g * 4;
      if constexpr (MODE == 0) {
#pragma unroll
        for (int i = 0; i < 4; ++i)
          store_out(C, (size_t)(row0 + i) * N + col, acc[rt][ct][i] + bv);
      } else {
        const int b = row0 >> 11, s0 = row0 & 2047;
        const int h = col >> 7, d = col & 127;
        u16 t4[4];
#pragma unroll
        for (int i = 0; i < 4; ++i) t4[i] = f2bf(acc[rt][ct][i] + bv);
        *(s16x4*)((u16*)C + ((size_t)(b * NKV + h) * HD + d) * SEQ + s0) =
            *(const s16x4*)t4;
      }
    }
  }
}

// O-proj with XCD-aware bijective remap (R10-R17-validated).
__global__ __launch_bounds__(256) void gemm_o(const u16* __restrict__ A,
                                              const u16* __restrict__ Bt,
                                              const float* __restrict__ bias,
                                              float* __restrict__ C) {
  __shared__ __align__(16) u16 As[128 * 64];
  __shared__ __align__(16) u16 Bs[128 * 64];
  const int d = blockIdx.x + blockIdx.y * 32;
  const int t = (d & 7) * 128 + (d >> 3);
  const int x = t >> 5, y = t & 31;
  gemm_body<float, 0>(A, Bt, bias, 1.0f, C, MR, EMB, EMB, y * 128, x * 128, As, Bs);
}

// Merged QKV projection with XCD remap (R9-R17-validated pointer selection).
__global__ __launch_bounds__(256) void gemm_proj(
    const u16* __restrict__ qb, const u16* __restrict__ kb, const u16* __restrict__ vb,
    const u16* __restrict__ Wqt, const u16* __restrict__ Wkt, const u16* __restrict__ Wvt,
    const float* __restrict__ bq, const float* __restrict__ bk, const float* __restrict__ bv,
    u16* __restrict__ Qp, u16* __restrict__ Kpp, u16* __restrict__ Vtt) {
  __shared__ __align__(16) u16 As[128 * 64];
  __shared__ __align__(16) u16 Bs[128 * 64];
  const int d = blockIdx.x + blockIdx.y * 48;
  const int t = (d & 7) * 192 + (d >> 3);
  const int x = t >> 5, y = t & 31;
  if (x < 32)
    gemm_body<u16, 0>(qb, Wqt, bq, SCL, Qp, MR, EMB, EMB, y * 128, x * 128, As, Bs);
  else if (x < 40)
    gemm_body<u16, 0>(kb, Wkt, bk, 1.0f, Kpp, MR, KVD, EMB, y * 128, (x - 32) * 128, As, Bs);
  else
    gemm_body<u16, 1>(vb, Wvt, bv, 1.0f, Vtt, MR, KVD, EMB, y * 128, (x - 40) * 128, As, Bs);
}

// ---------- flash attention (GQA), swapped-operand structure ----------
// R17-VERBATIM (passing, ~183us): R15 body + XCD-aware flat block-id decode.
// Structure FROZEN (structural edits 0/4 across the session).

__global__ __launch_bounds__(256, 2) void attn(const u16* __restrict__ Q,
                                               const u16* __restrict__ Kp,
                                               const u16* __restrict__ Vt,
                                               u16* __restrict__ Y) {
  __shared__ __align__(16) u16 Kb[2][64 * 128];   // [buf][kv][d]  (swizzled f=r&7)
  __shared__ __align__(16) u16 Vb[2][128 * 64];   // [buf][d][kv]  (swizzled f=r&7)

  const int tid = threadIdx.x, lane = tid & 63, w = tid >> 6;
  const int l15 = lane & 15, g = lane >> 4;
  const int d_ = blockIdx.x;
  const int t_ = (d_ & 7) * 128 + (d_ >> 3);      // XCD-aware bijective remap
  const int bz = t_ >> 4, b = bz >> 5, qh = bz & 31, h = qh >> 2;
  const int q0 = (t_ & 15) * 128;

  // Q fragments (B-operand layout: lane holds Q[q=l15][k=g*8..g*8+7])
  s16x8 qf[2][4];
  const u16* qptr = Q + (size_t)(b * SEQ + q0 + w * 32) * EMB + qh * HD;
#pragma unroll
  for (int rt = 0; rt < 2; ++rt)
#pragma unroll
    for (int ks = 0; ks < 4; ++ks)
      qf[rt][ks] = *(const s16x8*)(qptr + (size_t)(rt * 16 + l15) * EMB + ks * 32 + g * 8);

  const u16* kbase = Kp + (size_t)b * SEQ * KVD + h * HD;
  const u16* vbase = Vt + (size_t)(b * NKV + h) * HD * SEQ;

  // Stage one KV chunk into buf via global_load_lds (R2 verbatim).
  auto stage = [&](int buf, int kv0) {
#pragma unroll
    for (int p = 0; p < 4; ++p) {               // K: 64 rows x 128 u16
      int r = p * 16 + w * 4 + (lane >> 4);
      const u16* src = kbase + (size_t)(kv0 + r) * KVD + (((lane & 15) ^ (r & 7)) << 3);
      gload16(src, &Kb[buf][p * 2048 + w * 512]);
    }
#pragma unroll
    for (int p = 0; p < 4; ++p) {               // V^T: 128 rows x 64 u16
      int r = p * 32 + w * 8 + (lane >> 3);
      const u16* src = vbase + (size_t)r * SEQ + kv0 + (((lane & 7) ^ (r & 7)) << 3);
      gload16(src, &Vb[buf][p * 2048 + w * 512]);
    }
  };

  f32x4 o[2][8] = {};
  float m_[2] = {-1e30f, -1e30f}, l_[2] = {0.f, 0.f};

  stage(0, 0);
  __syncthreads();

  for (int t = 0; t < SEQ / 64; ++t) {
    const int cur = t & 1;
    if (t < SEQ / 64 - 1) stage(cur ^ 1, (t + 1) * 64);  // prefetch next chunk

    // ---- S^T = K Q^T  (4 kv col-tiles x 2 q row-tiles) ----
    f32x4 sacc[2][4] = {};
    __builtin_amdgcn_s_setprio(1);
#pragma unroll
    for (int ks = 0; ks < 4; ++ks) {
      s16x8 kf[4];
#pragma unroll
      for (int ct = 0; ct < 4; ++ct) {
        const int blk = ((ks << 2) | g) ^ (l15 & 7);
        kf[ct] = *(const s16x8*)&Kb[cur][(ct * 16 + l15) * 128 + (blk << 3)];
      }
#pragma unroll
      for (int rt = 0; rt < 2; ++rt)
#pragma unroll
        for (int ct = 0; ct < 4; ++ct)
          mfma_acc(sacc[rt][ct], kf[ct], qf[rt][ks]);
    }
    __builtin_amdgcn_s_setprio(0);

    // ---- online softmax (scores already in log2 domain): defer-max, per-lane l ----
    s16x8 pvf[2][2];
#pragma unroll
    for (int rt = 0; rt < 2; ++rt) {
      float t0 = fmaxf(fmaxf(sacc[rt][0][0], sacc[rt][0][1]),
                       fmaxf(sacc[rt][0][2], sacc[rt][0][3]));
      float t1 = fmaxf(fmaxf(sacc[rt][1][0], sacc[rt][1][1]),
                       fmaxf(sacc[rt][1][2], sacc[rt][1][3]));
      float t2 = fmaxf(fmaxf(sacc[rt][2][0], sacc[rt][2][1]),
                       fmaxf(sacc[rt][2][2], sacc[rt][2][3]));
      float t3 = fmaxf(fmaxf(sacc[rt][3][0], sacc[rt][3][1]),
                       fmaxf(sacc[rt][3][2], sacc[rt][3][3]));
      const float pm = fmaxf(fmaxf(t0, t1), fmaxf(t2, t3));

      if (!__all(pm - m_[rt] <= 8.f)) {        // rare: genuine max growth
        float mr = pm;
        mr = fmaxf(mr, __shfl_xor(mr, 16));
        mr = fmaxf(mr, __shfl_xor(mr, 32));
        const float mn = fmaxf(m_[rt], mr);
        const float al = fexp2(m_[rt] - mn);
        m_[rt] = mn;
        l_[rt] *= al;
#pragma unroll
        for (int dt = 0; dt < 8; ++dt) {
          o[rt][dt][0] *= al; o[rt][dt][1] *= al;
          o[rt][dt][2] *= al; o[rt][dt][3] *= al;
        }
      }
      const float mcur = m_[rt];

      float rs = 0.f;
      int wd[4][2];
#pragma unroll
      for (int ct = 0; ct < 4; ++ct) {
        float p0 = fexp2(sacc[rt][ct][0] - mcur);
        float p1 = fexp2(sacc[rt][ct][1] - mcur);
        float p2 = fexp2(sacc[rt][ct][2] - mcur);
        float p3 = fexp2(sacc[rt][ct][3] - mcur);
        rs += (p0 + p1) + (p2 + p3);
        asm("v_cvt_pk_bf16_f32 %0, %1, %2" : "=v"(wd[ct][0]) : "v"(p0), "v"(p1));
        asm("v_cvt_pk_bf16_f32 %0, %1, %2" : "=v"(wd[ct][1]) : "v"(p2), "v"(p3));
      }
      l_[rt] += rs;                            // per-lane partial; reduced in epilogue

      // route P^T into PV B-fragments: target lane [g1,g0] word (u,s) <- reg
      // (g1,s) lane [g0,u]; swap32 then swap16 realizes the quarter permutation.
#pragma unroll
      for (int ks2 = 0; ks2 < 2; ++ks2) {
        union { int w4[4]; s16x8 v; } u;
#pragma unroll
        for (int s = 0; s < 2; ++s) {
          int x = wd[2 * ks2][s], y = wd[2 * ks2 + 1][s];
          asm volatile("v_permlane32_swap_b32 %0, %1" : "+v"(x), "+v"(y));
          asm volatile("v_permlane16_swap_b32 %0, %1" : "+v"(x), "+v"(y));
          u.w4[s] = x; u.w4[2 + s] = y;
        }
        pvf[rt][ks2] = u.v;
      }
    }

    // ---- O^T += V^T P^T ----
    __builtin_amdgcn_s_setprio(1);
#pragma unroll
    for (int ks2 = 0; ks2 < 2; ++ks2)
#pragma unroll
      for (int dt = 0; dt < 8; ++dt) {
        const int blk = ((ks2 << 2) | g) ^ (l15 & 7);
        const s16x8 vf = *(const s16x8*)&Vb[cur][(dt * 16 + l15) * 64 + (blk << 3)];
        mfma_acc(o[0][dt], vf, pvf[0][ks2]);
        mfma_acc(o[1][dt], vf, pvf[1][ks2]);
      }
    __builtin_amdgcn_s_setprio(0);

    __syncthreads();   // staged chunk t+1 visible; all reads of buf done
  }

  // ---- epilogue: reduce l across g-lanes once, then 8B vector stores ----
  u16* ybase = Y + (size_t)(b * SEQ + q0 + w * 32) * EMB + qh * HD;
#pragma unroll
  for (int rt = 0; rt < 2; ++rt) {
    float lt = l_[rt];
    lt += __shfl_xor(lt, 16);
    lt += __shfl_xor(lt, 32);
    const float inv = 1.f / lt;
    u16* yr = ybase + (size_t)(rt * 16 + l15) * EMB + g * 4;
#pragma unroll
    for (int dt = 0; dt < 8; ++dt) {
      u16 t4[4];
#pragma unroll
      for (int i = 0; i < 4; ++i) t4[i] = f2bf(o[rt][dt][i] * inv);
      *(s16x4*)(yr + dt * 16) = *(const s16x4*)t4;
    }
  }
}

// ---------- launch ----------

extern "C" void kernel_launch(void* const* d_in, const int* in_sizes, int n_in,
                              void* d_out, int out_size, void* d_ws, size_t ws_size,
                              hipStream_t stream) {
  (void)in_sizes; (void)n_in; (void)out_size;
  const float* q_in = (const float*)d_in[0];
  const float* k_in = (const float*)d_in[1];
  const float* v_in = (const float*)d_in[2];
  const float* Wq = (const float*)d_in[3];
  const float* bq = (const float*)d_in[4];
  const float* Wk = (const float*)d_in[5];
  const float* bk = (const float*)d_in[6];
  const float* Wv = (const float*)d_in[7];
  const float* bv = (const float*)d_in[8];
  const float* Wo = (const float*)d_in[9];
  const float* bo = (const float*)d_in[10];
  float* out = (float*)d_out;

  char* base = (char*)d_ws;
  size_t off = 0;
  auto alloc = [&](size_t bytes) -> void* {
    void* r = base + off;
    off += (bytes + 255) & ~(size_t)255;
    return r;
  };
  u16* qb  = (u16*)alloc((size_t)MR * EMB * 2);
  u16* kb  = (u16*)alloc((size_t)MR * EMB * 2);
  u16* vb  = (u16*)alloc((size_t)MR * EMB * 2);
  u16* Wqt = (u16*)alloc((size_t)EMB * EMB * 2);
  u16* Wkt = (u16*)alloc((size_t)KVD * EMB * 2);
  u16* Wvt = (u16*)alloc((size_t)KVD * EMB * 2);
  u16* Wot = (u16*)alloc((size_t)EMB * EMB * 2);
  u16* Qp  = (u16*)alloc((size_t)MR * EMB * 2);
  u16* Kpp = (u16*)alloc((size_t)MR * KVD * 2);
  u16* Vtt = (u16*)alloc((size_t)MR * KVD * 2);
  u16* Y   = qb;  // qb dead after Q projection
  if (off > ws_size) return;  // loud failure instead of OOB corruption

  prep<<<65536, 256, 0, stream>>>(q_in, k_in, v_in, qb, kb, vb,
                                  Wq, Wo, Wk, Wv, Wqt, Wot, Wkt, Wvt);

  gemm_proj<<<dim3(48, 32), 256, 0, stream>>>(qb, kb, vb, Wqt, Wkt, Wvt,
                                              bq, bk, bv, Qp, Kpp, Vtt);
  attn<<<1024, 256, 0, stream>>>(Qp, Kpp, Vtt, Y);
  gemm_o<<<dim3(32, 32), 256, 0, stream>>>(Y, Wot, bo, out);
}